// Round 11
// baseline (5552.263 us; speedup 1.0000x reference)
//
#include <hip/hip_runtime.h>

#define NUM_ITERS 15
#define BB 2
#define NN 2048
#define QQ 256
#define CHUNKS 16          // colsum n-chunks of 128 rows

// ---------------------------------------------------------------------------
// Numerical contract (matches numpy-fp32 golden; verified absmax 0.00195 in
// R8/R9/R10 — LOAD-BEARING, do not relax):
//  - no FMA contraction (pragma clang fp contract(off))
//  - GEMM per output element: single fp32 accumulator, strictly ascending k,
//    round(mul) then round(add), final true division by max(sum,1)
//  - row reductions over q=256: numpy pairwise tree (8-acc blocks of 128,
//    fixed combine), association order replicated exactly
//  - colsum: ascending-n in 16 chunks, combined ascending
// ---------------------------------------------------------------------------

__global__ __launch_bounds__(256) void colsum_part(
    const float* __restrict__ adj, const float* __restrict__ act,
    float* __restrict__ pe0, float* __restrict__ pi0,
    float* __restrict__ pe1, float* __restrict__ pi1)
{
#pragma clang fp contract(off)
    const int b = (int)blockIdx.z;
    const int c = (int)blockIdx.y;
    const int m = (int)blockIdx.x * 256 + (int)threadIdx.x;
    const float* src = adj + (size_t)b * NN * NN;
    const float* ab  = act + (size_t)b * NN;
    float se0 = 0.0f, si0 = 0.0f, se1 = 0.0f, si1 = 0.0f;
    const int n0 = c * (NN / CHUNKS);
    for (int n = n0; n < n0 + NN / CHUNKS; ++n) {
        float x = src[(size_t)n * NN + m];
        float e = (x > 0.5f) ? x : 0.0f;
        float v = 1.0f - x;
        float iv = (v > 0.5f) ? v : 0.0f;
        float av = ab[n];
        se1 = se1 + e;
        si1 = si1 + iv;
        se0 = se0 + e * av;
        si0 = si0 + iv * av;
    }
    size_t o = ((size_t)c * BB + b) * NN + m;
    pe0[o] = se0; pi0[o] = si0; pe1[o] = se1; pi1[o] = si1;
}

__global__ __launch_bounds__(256) void colsum_combine(
    const float* __restrict__ pe0, const float* __restrict__ pi0,
    const float* __restrict__ pe1, const float* __restrict__ pi1,
    float* __restrict__ se0, float* __restrict__ si0,
    float* __restrict__ se1, float* __restrict__ si1)
{
#pragma clang fp contract(off)
    const int i = (int)blockIdx.x * 256 + (int)threadIdx.x;   // 0..BB*NN-1
    float a = 0.0f, bb = 0.0f, cc = 0.0f, dd = 0.0f;
    for (int c = 0; c < CHUNKS; ++c) {
        size_t o = (size_t)c * (BB * NN) + i;
        a  = a  + pe0[o];
        bb = bb + pi0[o];
        cc = cc + pe1[o];
        dd = dd + pi1[o];
    }
    se0[i] = a; si0[i] = bb; se1[i] = cc; si1[i] = dd;
}

// ---------------------------------------------------------------------------
// Fused thresholded GEMM, np-fp32-exact per-element chain:
//   C[m][q] = sum_k (thr(adj[k][m]) * act[k]) * hsrc[k][q]   (ascending k)
//   mode 0: dst = h_old + C/max(sum,1);  mode 1: dst = C/max(sum,1)
// Tile M=64 x Q=64, BK=64, 256 threads (16x16), thread computes 4x4.
// Grid (NN/64, QQ/64, BB) = 256 blocks = 1 block/CU; register-prefetch
// staging hides global latency under the compute phase.
// LDS-traffic analysis: 4x4 blocking = 0.5 words/MAC (half of 2x2) ->
// ~82 us LDS floor vs 55 us VALU floor per GEMM dispatch.
// ---------------------------------------------------------------------------
__global__ __launch_bounds__(256, 1) void gemm_fused(
    const float* __restrict__ adj,
    const float* __restrict__ hsrc,
    const float* act,
    const float* __restrict__ sums,
    const float* h_old,
    float* __restrict__ dst,
    int mode)
{
#pragma clang fp contract(off)
    __shared__ float Ws[64][68];
    __shared__ float Hs[64][68];

    const int b  = (int)blockIdx.z;
    const int m0 = (int)blockIdx.x * 64;
    const int q0 = (int)blockIdx.y * 64;
    const int tid = (int)threadIdx.x;
    const int tm4 = (tid & 15) * 4;
    const int tq4 = (tid >> 4) * 4;

    const float* adjb = adj + (size_t)b * NN * NN;
    const float* hb   = hsrc + (size_t)b * NN * QQ;
    const float* ab   = (act != 0) ? (act + (size_t)b * NN) : (const float*)0;

    float acc[4][4];
    #pragma unroll
    for (int i = 0; i < 4; ++i)
        #pragma unroll
        for (int j = 0; j < 4; ++j)
            acc[i][j] = 0.0f;

    float rw[16], rh[16];

    // prologue: prefetch k-block 0 into registers
    #pragma unroll
    for (int i = 0; i < 16; ++i) {
        int idx = tid + 256 * i;
        int kk = idx >> 6;        // 0..63
        int mm = idx & 63;        // 0..63
        rw[i] = adjb[(size_t)kk * NN + m0 + mm];
        rh[i] = hb[(size_t)kk * QQ + q0 + mm];
    }

    for (int kb = 0; kb < NN / 64; ++kb) {
        __syncthreads();   // previous tile's compute done before overwrite
        #pragma unroll
        for (int i = 0; i < 16; ++i) {
            int idx = tid + 256 * i;
            int kk = idx >> 6;
            int mm = idx & 63;
            float x = rw[i];
            float wgt;
            if (mode == 0) {
                wgt = (x > 0.5f) ? x : 0.0f;
            } else {
                float v = 1.0f - x;
                wgt = (v > 0.5f) ? v : 0.0f;
            }
            if (ab != 0) wgt = wgt * ab[kb * 64 + kk];
            Ws[kk][mm] = wgt;
            Hs[kk][mm] = rh[i];
        }
        __syncthreads();
        if (kb + 1 < NN / 64) {
            const int k0n = (kb + 1) * 64;
            #pragma unroll
            for (int i = 0; i < 16; ++i) {
                int idx = tid + 256 * i;
                int kk = idx >> 6;
                int mm = idx & 63;
                rw[i] = adjb[(size_t)(k0n + kk) * NN + m0 + mm];
                rh[i] = hb[(size_t)(k0n + kk) * QQ + q0 + mm];
            }
        }
        #pragma unroll 8
        for (int kk = 0; kk < 64; ++kk) {
            float a0 = Ws[kk][tm4 + 0];
            float a1 = Ws[kk][tm4 + 1];
            float a2 = Ws[kk][tm4 + 2];
            float a3 = Ws[kk][tm4 + 3];
            float b0 = Hs[kk][tq4 + 0];
            float b1 = Hs[kk][tq4 + 1];
            float b2 = Hs[kk][tq4 + 2];
            float b3 = Hs[kk][tq4 + 3];
            acc[0][0] = acc[0][0] + a0 * b0; acc[0][1] = acc[0][1] + a0 * b1;
            acc[0][2] = acc[0][2] + a0 * b2; acc[0][3] = acc[0][3] + a0 * b3;
            acc[1][0] = acc[1][0] + a1 * b0; acc[1][1] = acc[1][1] + a1 * b1;
            acc[1][2] = acc[1][2] + a1 * b2; acc[1][3] = acc[1][3] + a1 * b3;
            acc[2][0] = acc[2][0] + a2 * b0; acc[2][1] = acc[2][1] + a2 * b1;
            acc[2][2] = acc[2][2] + a2 * b2; acc[2][3] = acc[2][3] + a2 * b3;
            acc[3][0] = acc[3][0] + a3 * b0; acc[3][1] = acc[3][1] + a3 * b1;
            acc[3][2] = acc[3][2] + a3 * b2; acc[3][3] = acc[3][3] + a3 * b3;
        }
    }

    #pragma unroll
    for (int i = 0; i < 4; ++i) {
        int row = m0 + tm4 + i;
        float s = sums[b * NN + row];
        if (s < 1.0f) s = 1.0f;
        size_t gbase = ((size_t)b * NN + row) * QQ + q0 + tq4;
        #pragma unroll
        for (int j = 0; j < 4; ++j) {
            float v = acc[i][j] / s;
            if (mode == 0) {
                dst[gbase + j] = h_old[gbase + j] + v;
            } else {
                dst[gbase + j] = v;
            }
        }
    }
}

// ---------------------------------------------------------------------------
// Projection + relu + L2-normalize, np-fp32-exact, in place on h_io.
// Pairwise trees parallelized with IDENTICAL association order.
// Block = one row m (256 threads). Grid (NN, BB).
// ---------------------------------------------------------------------------
__global__ __launch_bounds__(256) void project_kernel(
    float* h_io, const float* __restrict__ ieff)
{
#pragma clang fp contract(off)
    __shared__ float sp[256];
    __shared__ float sq[256];
    __shared__ float rs[32];
    __shared__ float sc[2];
    const int b = (int)blockIdx.y;
    const int m = (int)blockIdx.x;
    const int t = (int)threadIdx.x;

    size_t gi = ((size_t)b * NN + m) * QQ + t;
    float hv = h_io[gi];
    float ie = ieff[gi];

    sp[t] = hv * ie;
    sq[t] = ie * ie;
    __syncthreads();
    if (t < 32) {
        const float* a = (t < 16) ? sp : sq;
        int j = t & 7;
        int base = (t & 8) ? 128 : 0;
        float r = a[base + j];
        for (int i = 8; i < 128; i += 8) r = r + a[base + i + j];
        rs[t] = r;
    }
    __syncthreads();
    if (t == 0) {
        float d0 = ((rs[0] + rs[1]) + (rs[2] + rs[3])) + ((rs[4] + rs[5]) + (rs[6] + rs[7]));
        float d1 = ((rs[8] + rs[9]) + (rs[10] + rs[11])) + ((rs[12] + rs[13]) + (rs[14] + rs[15]));
        float dot = d0 + d1;
        float u0 = ((rs[16] + rs[17]) + (rs[18] + rs[19])) + ((rs[20] + rs[21]) + (rs[22] + rs[23]));
        float u1 = ((rs[24] + rs[25]) + (rs[26] + rs[27])) + ((rs[28] + rs[29]) + (rs[30] + rs[31]));
        float un = u0 + u1;
        sc[0] = dot / (un + 1e-12f);
    }
    __syncthreads();
    float c = sc[0];
    float tmp = c * ie;
    float h2 = hv - tmp;
    float r = (h2 > 0.0f) ? h2 : 0.0f;
    sp[t] = r * r;
    __syncthreads();
    if (t < 16) {
        int j = t & 7;
        int base = (t & 8) ? 128 : 0;
        float rr = sp[base + j];
        for (int i = 8; i < 128; i += 8) rr = rr + sp[base + i + j];
        rs[t] = rr;
    }
    __syncthreads();
    if (t == 0) {
        float n0 = ((rs[0] + rs[1]) + (rs[2] + rs[3])) + ((rs[4] + rs[5]) + (rs[6] + rs[7]));
        float n1 = ((rs[8] + rs[9]) + (rs[10] + rs[11])) + ((rs[12] + rs[13]) + (rs[14] + rs[15]));
        float nn = n0 + n1;
        float den = (float)sqrt((double)nn);
        if (den < 1e-8f) den = 1e-8f;
        sc[1] = den;
    }
    __syncthreads();
    h_io[gi] = r / sc[1];
}

// ---------------------------------------------------------------------------
extern "C" void kernel_launch(void* const* d_in, const int* in_sizes, int n_in,
                              void* d_out, int out_size, void* d_ws, size_t ws_size,
                              hipStream_t stream)
{
    const float* h0     = 0;
    const float* adj    = 0;
    const float* act_in = 0;
    for (int i = 0; i < n_in; ++i) {
        if (in_sizes[i] == BB * NN * QQ)      h0     = (const float*)d_in[i];
        else if (in_sizes[i] == BB * NN * NN) adj    = (const float*)d_in[i];
        else if (in_sizes[i] == BB * NN)      act_in = (const float*)d_in[i];
    }
    float* out = (float*)d_out;

    char* ws = (char*)d_ws;
    size_t off = 0;
    float* ieff = (float*)(ws + off); off += (size_t)BB * NN * QQ * 4;      // 4 MB
    float* pe0 = (float*)(ws + off); off += (size_t)CHUNKS * BB * NN * 4;   // 256 KB
    float* pi0 = (float*)(ws + off); off += (size_t)CHUNKS * BB * NN * 4;
    float* pe1 = (float*)(ws + off); off += (size_t)CHUNKS * BB * NN * 4;
    float* pi1 = (float*)(ws + off); off += (size_t)CHUNKS * BB * NN * 4;
    float* sum_e0 = (float*)(ws + off); off += (size_t)BB * NN * 4;
    float* sum_i0 = (float*)(ws + off); off += (size_t)BB * NN * 4;
    float* sum_e1 = (float*)(ws + off); off += (size_t)BB * NN * 4;
    float* sum_i1 = (float*)(ws + off); off += (size_t)BB * NN * 4;

    const size_t slice_sz = (size_t)BB * NN * QQ;

    colsum_part<<<dim3(NN / 256, CHUNKS, BB), 256, 0, stream>>>(
        adj, act_in, pe0, pi0, pe1, pi1);
    colsum_combine<<<dim3(BB * NN / 256), 256, 0, stream>>>(
        pe0, pi0, pe1, pi1, sum_e0, sum_i0, sum_e1, sum_i1);

    for (int it = 0; it < NUM_ITERS; ++it) {
        const float* act = (it == 0) ? act_in : (const float*)0;
        const float* se  = (it == 0) ? sum_e0 : sum_e1;
        const float* si  = (it == 0) ? sum_i0 : sum_i1;
        const float* h_prev = (it == 0) ? h0 : (out + (size_t)(it - 1) * slice_sz);
        float* h_cur = out + (size_t)it * slice_sz;

        // h_cur = h_prev + e_eff   (excite)
        gemm_fused<<<dim3(NN / 64, QQ / 64, BB), 256, 0, stream>>>(
            adj, h_prev, act, se, h_prev, h_cur, 0);
        // ieff from updated h     (inhibit)
        gemm_fused<<<dim3(NN / 64, QQ / 64, BB), 256, 0, stream>>>(
            adj, h_cur, act, si, (const float*)0, ieff, 1);
        // projection + relu + normalize (np-exact), in place
        project_kernel<<<dim3(NN, BB), 256, 0, stream>>>(h_cur, ieff);
    }
}